// Round 1
// baseline (2106.885 us; speedup 1.0000x reference)
//
#include <hip/hip_runtime.h>

// AtomicScaleModule: CGCNN-style GNN forward, algebraically restructured.
//   a = atom_fea @ ae_w + ae_b
//   per layer l:
//     s = a @ msg_w1[l][0:64] + msg_b1[l]          (k_st)
//     t = a @ msg_w1[l][64:128]                    (k_st)
//     H = sum_c relu(s[n] + t[idx[n,c]])           (k_conv)
//     agg = H @ msg_w2[l] + 12*msg_b2[l]           (k_conv)
//     u1  = relu(a@upd_w1[l][0:64] + agg@upd_w1[l][64:128] + upd_b1[l])
//     a   = relu(a + u1 @ upd_w2[l] + upd_b2[l])   (k_conv)
//   af = relu(a @ fx_w1 + fx_b1) @ fx_w2 + fx_b2 ; props = af @ prop_w^T + prop_b
// nbr_fea / ne_w / ne_b are dead in the reference (computed but unused).

constexpr int NA  = 300000;
constexpr int BLK = 128;

#define DEVFN __device__ __forceinline__

DEVFN float4 ld4(const float* p) { return *(const float4*)p; }
DEVFN void   st4(float* p, float4 v) { *(float4*)p = v; }
DEVFN void   fma4(float4& a, float s, float4 w) {
  a.x += s * w.x; a.y += s * w.y; a.z += s * w.z; a.w += s * w.w;
}
DEVFN float4 add4(float4 a, float4 b) {
  return make_float4(a.x + b.x, a.y + b.y, a.z + b.z, a.w + b.w);
}
DEVFN float4 relu4(float4 v) {
  return make_float4(fmaxf(v.x, 0.f), fmaxf(v.y, 0.f), fmaxf(v.z, 0.f), fmaxf(v.w, 0.f));
}

// acc[16] (64 outputs) += x (64 values, in regs) @ W[64][64], using a private
// LDS column xs[k][tid] so the dynamic k-loop never indexes a register array.
DEVFN void mv64(const float* __restrict__ W, float (*xs)[BLK], int t,
                const float4 (&x)[16], float4 (&acc)[16]) {
#pragma unroll
  for (int i = 0; i < 16; ++i) {
    xs[4 * i + 0][t] = x[i].x; xs[4 * i + 1][t] = x[i].y;
    xs[4 * i + 2][t] = x[i].z; xs[4 * i + 3][t] = x[i].w;
  }
#pragma unroll 1
  for (int k = 0; k < 64; k += 4) {
    float x0 = xs[k][t], x1 = xs[k + 1][t], x2 = xs[k + 2][t], x3 = xs[k + 3][t];
    const float* w = W + k * 64;
#pragma unroll
    for (int j = 0; j < 16; ++j) {
      fma4(acc[j], x0, ld4(w + j * 4));
      fma4(acc[j], x1, ld4(w + 64 + j * 4));
      fma4(acc[j], x2, ld4(w + 128 + j * 4));
      fma4(acc[j], x3, ld4(w + 192 + j * 4));
    }
  }
}

__global__ __launch_bounds__(BLK) void k_embed(const float* __restrict__ X,
                                               const float* __restrict__ W,
                                               const float* __restrict__ b,
                                               float* __restrict__ A0) {
  int n = blockIdx.x * BLK + threadIdx.x;
  if (n >= NA) return;
  float4 acc[16];
#pragma unroll
  for (int j = 0; j < 16; ++j) acc[j] = ld4(b + j * 4);
  const float* xr = X + (size_t)n * 92;
#pragma unroll 1
  for (int k = 0; k < 92; k += 4) {
    float4 x4 = ld4(xr + k);
    float xv[4] = {x4.x, x4.y, x4.z, x4.w};
    const float* w = W + k * 64;
#pragma unroll
    for (int kk = 0; kk < 4; ++kk) {
#pragma unroll
      for (int j = 0; j < 16; ++j) fma4(acc[j], xv[kk], ld4(w + kk * 64 + j * 4));
    }
  }
  float* ar = A0 + (size_t)n * 64;
#pragma unroll
  for (int j = 0; j < 16; ++j) st4(ar + j * 4, acc[j]);
}

// s = a @ W1[0:64] + b1 ; t = a @ W1[64:128]
__global__ __launch_bounds__(BLK) void k_st(const float* __restrict__ Ain,
                                            const float* __restrict__ W1,
                                            const float* __restrict__ b1,
                                            float* __restrict__ S,
                                            float* __restrict__ T) {
  int n = blockIdx.x * BLK + threadIdx.x;
  if (n >= NA) return;
  float4 as_[16], at_[16];
#pragma unroll
  for (int j = 0; j < 16; ++j) { as_[j] = ld4(b1 + j * 4); at_[j] = make_float4(0, 0, 0, 0); }
  const float* arp = Ain + (size_t)n * 64;
#pragma unroll 1
  for (int k = 0; k < 64; k += 4) {
    float4 x4 = ld4(arp + k);
    float xv[4] = {x4.x, x4.y, x4.z, x4.w};
    const float* ws = W1 + k * 64;
    const float* wt = W1 + (64 + k) * 64;
#pragma unroll
    for (int kk = 0; kk < 4; ++kk) {
#pragma unroll
      for (int j = 0; j < 16; ++j) {
        fma4(as_[j], xv[kk], ld4(ws + kk * 64 + j * 4));
        fma4(at_[j], xv[kk], ld4(wt + kk * 64 + j * 4));
      }
    }
  }
  float* sp = S + (size_t)n * 64;
  float* tp = T + (size_t)n * 64;
#pragma unroll
  for (int j = 0; j < 16; ++j) { st4(sp + j * 4, as_[j]); st4(tp + j * 4, at_[j]); }
}

__global__ __launch_bounds__(BLK) void k_conv(const float* __restrict__ Ain,
                                              const float* __restrict__ S,
                                              const float* __restrict__ T,
                                              const int* __restrict__ IDX,
                                              const float* __restrict__ W2,
                                              const float* __restrict__ b2,
                                              const float* __restrict__ U1,
                                              const float* __restrict__ ub1,
                                              const float* __restrict__ U2,
                                              const float* __restrict__ ub2,
                                              float* __restrict__ Aout) {
  __shared__ float xs[64][BLK];
  int n = blockIdx.x * BLK + threadIdx.x;
  if (n >= NA) return;
  int t = threadIdx.x;

  // H = sum_c relu(s + t[idx[c]])
  float4 sr[16];
#pragma unroll
  for (int j = 0; j < 16; ++j) sr[j] = ld4(S + (size_t)n * 64 + j * 4);
  float4 ha[16];
#pragma unroll
  for (int j = 0; j < 16; ++j) ha[j] = make_float4(0, 0, 0, 0);
  int4 i0 = *(const int4*)(IDX + (size_t)n * 12);
  int4 i1 = *(const int4*)(IDX + (size_t)n * 12 + 4);
  int4 i2 = *(const int4*)(IDX + (size_t)n * 12 + 8);
  int idxs[12] = {i0.x, i0.y, i0.z, i0.w, i1.x, i1.y, i1.z, i1.w, i2.x, i2.y, i2.z, i2.w};
#pragma unroll
  for (int c = 0; c < 12; ++c) {
    const float* tr = T + (size_t)idxs[c] * 64;
#pragma unroll
    for (int j = 0; j < 16; ++j) ha[j] = add4(ha[j], relu4(add4(sr[j], ld4(tr + j * 4))));
  }

  // agg = H @ W2 + 12*b2
  float4 agg[16];
#pragma unroll
  for (int j = 0; j < 16; ++j) {
    float4 b = ld4(b2 + j * 4);
    agg[j] = make_float4(12.f * b.x, 12.f * b.y, 12.f * b.z, 12.f * b.w);
  }
  mv64(W2, xs, t, ha, agg);

  // u1 = relu(a @ U1[0:64] + agg @ U1[64:128] + ub1)
  float4 ar[16];
#pragma unroll
  for (int j = 0; j < 16; ++j) ar[j] = ld4(Ain + (size_t)n * 64 + j * 4);
  float4 u1[16];
#pragma unroll
  for (int j = 0; j < 16; ++j) u1[j] = ld4(ub1 + j * 4);
  mv64(U1, xs, t, ar, u1);
  mv64(U1 + 64 * 64, xs, t, agg, u1);
#pragma unroll
  for (int j = 0; j < 16; ++j) u1[j] = relu4(u1[j]);

  // a_new = relu(a + u1 @ U2 + ub2)
  float4 upd[16];
#pragma unroll
  for (int j = 0; j < 16; ++j) upd[j] = ld4(ub2 + j * 4);
  mv64(U2, xs, t, u1, upd);
  float* ao = Aout + (size_t)n * 64;
#pragma unroll
  for (int j = 0; j < 16; ++j) st4(ao + j * 4, relu4(add4(ar[j], upd[j])));
}

__global__ __launch_bounds__(BLK) void k_fx(const float* __restrict__ Araw,
                                            const float* __restrict__ W1,  // [64][128]
                                            const float* __restrict__ b1,  // [128]
                                            const float* __restrict__ W2,  // [128][64]
                                            const float* __restrict__ b2,  // [64]
                                            const float* __restrict__ PW,  // [4][64]
                                            const float* __restrict__ PB,  // [4]
                                            float* __restrict__ AF,
                                            float* __restrict__ PR) {
  __shared__ float xs[64][BLK];
  int n = blockIdx.x * BLK + threadIdx.x;
  if (n >= NA) return;
  int t = threadIdx.x;

  float4 ar[16];
#pragma unroll
  for (int j = 0; j < 16; ++j) ar[j] = ld4(Araw + (size_t)n * 64 + j * 4);

  // h = relu(ar @ W1 + b1), 128 wide
  float4 h[32];
#pragma unroll
  for (int j = 0; j < 32; ++j) h[j] = ld4(b1 + j * 4);
#pragma unroll
  for (int i = 0; i < 16; ++i) {
    xs[4 * i + 0][t] = ar[i].x; xs[4 * i + 1][t] = ar[i].y;
    xs[4 * i + 2][t] = ar[i].z; xs[4 * i + 3][t] = ar[i].w;
  }
#pragma unroll 1
  for (int k = 0; k < 64; k += 2) {
    float x0 = xs[k][t], x1 = xs[k + 1][t];
    const float* w = W1 + k * 128;
#pragma unroll
    for (int j = 0; j < 32; ++j) {
      fma4(h[j], x0, ld4(w + j * 4));
      fma4(h[j], x1, ld4(w + 128 + j * 4));
    }
  }
#pragma unroll
  for (int j = 0; j < 32; ++j) h[j] = relu4(h[j]);

  // af = h @ W2 + b2  (K=128 in two halves through the LDS slot)
  float4 af[16];
#pragma unroll
  for (int j = 0; j < 16; ++j) af[j] = ld4(b2 + j * 4);
#pragma unroll
  for (int half = 0; half < 2; ++half) {
#pragma unroll
    for (int i = 0; i < 16; ++i) {
      float4 v = h[half * 16 + i];
      xs[4 * i + 0][t] = v.x; xs[4 * i + 1][t] = v.y;
      xs[4 * i + 2][t] = v.z; xs[4 * i + 3][t] = v.w;
    }
    const float* Wb = W2 + half * 64 * 64;
#pragma unroll 1
    for (int k = 0; k < 64; k += 4) {
      float x0 = xs[k][t], x1 = xs[k + 1][t], x2 = xs[k + 2][t], x3 = xs[k + 3][t];
      const float* w = Wb + k * 64;
#pragma unroll
      for (int j = 0; j < 16; ++j) {
        fma4(af[j], x0, ld4(w + j * 4));
        fma4(af[j], x1, ld4(w + 64 + j * 4));
        fma4(af[j], x2, ld4(w + 128 + j * 4));
        fma4(af[j], x3, ld4(w + 192 + j * 4));
      }
    }
  }

  // props = af @ PW^T + PB
  float pr[4];
#pragma unroll
  for (int p = 0; p < 4; ++p) {
    float s = PB[p];
#pragma unroll
    for (int i = 0; i < 16; ++i) {
      float4 w = ld4(PW + p * 64 + i * 4);
      s += af[i].x * w.x + af[i].y * w.y + af[i].z * w.z + af[i].w * w.w;
    }
    pr[p] = s;
  }

  float* afp = AF + (size_t)n * 64;
#pragma unroll
  for (int j = 0; j < 16; ++j) st4(afp + j * 4, af[j]);
  st4(PR + (size_t)n * 4, make_float4(pr[0], pr[1], pr[2], pr[3]));
}

extern "C" void kernel_launch(void* const* d_in, const int* in_sizes, int n_in,
                              void* d_out, int out_size, void* d_ws, size_t ws_size,
                              hipStream_t stream) {
  const float* atom_fea = (const float*)d_in[0];
  // d_in[1] nbr_fea, d_in[5] ne_w, d_in[6] ne_b: dead in the reference
  const int*   nbr_idx  = (const int*)d_in[2];
  const float* ae_w   = (const float*)d_in[3];
  const float* ae_b   = (const float*)d_in[4];
  const float* msg_w1 = (const float*)d_in[7];
  const float* msg_b1 = (const float*)d_in[8];
  const float* msg_w2 = (const float*)d_in[9];
  const float* msg_b2 = (const float*)d_in[10];
  const float* upd_w1 = (const float*)d_in[11];
  const float* upd_b1 = (const float*)d_in[12];
  const float* upd_w2 = (const float*)d_in[13];
  const float* upd_b2 = (const float*)d_in[14];
  const float* fx_w1  = (const float*)d_in[15];
  const float* fx_b1  = (const float*)d_in[16];
  const float* fx_w2  = (const float*)d_in[17];
  const float* fx_b2  = (const float*)d_in[18];
  const float* prop_w = (const float*)d_in[19];
  const float* prop_b = (const float*)d_in[20];

  float* props   = (float*)d_out;                 // [NA,4]
  float* af_reg  = props + (size_t)NA * 4;        // [NA,64]
  float* raw_reg = af_reg + (size_t)NA * 64;      // [NA,64]
  float* S = (float*)d_ws;                        // [NA,64]
  float* T = S + (size_t)NA * 64;                 // [NA,64]

  dim3 grid((NA + BLK - 1) / BLK), block(BLK);

  k_embed<<<grid, block, 0, stream>>>(atom_fea, ae_w, ae_b, af_reg);

  float* a_cur = af_reg;
  float* a_nxt = raw_reg;
  for (int l = 0; l < 3; ++l) {
    k_st<<<grid, block, 0, stream>>>(a_cur, msg_w1 + (size_t)l * 128 * 64,
                                     msg_b1 + (size_t)l * 64, S, T);
    k_conv<<<grid, block, 0, stream>>>(a_cur, S, T, nbr_idx,
                                       msg_w2 + (size_t)l * 64 * 64, msg_b2 + (size_t)l * 64,
                                       upd_w1 + (size_t)l * 128 * 64, upd_b1 + (size_t)l * 64,
                                       upd_w2 + (size_t)l * 64 * 64, upd_b2 + (size_t)l * 64,
                                       a_nxt);
    float* tmp = a_cur; a_cur = a_nxt; a_nxt = tmp;
  }
  // a_cur == raw_reg here: holds the final conv features ("raw" output)
  k_fx<<<grid, block, 0, stream>>>(a_cur, fx_w1, fx_b1, fx_w2, fx_b2,
                                   prop_w, prop_b, af_reg, props);
}